// Round 2
// baseline (240.888 us; speedup 1.0000x reference)
//
#include <hip/hip_runtime.h>

// y[i,j] = x[i,j] * w[j] + b[j], all FP32.
// x: (8192, 4096) fp32, w/b: (4096,) fp32, out: (8192, 4096) fp32.
// Pure streaming: 128 MiB read + 128 MiB write -> HBM-bound, floor ~43 us @ 6.3 TB/s
// (m13 float4-copy ceiling). Timed region also contains ~2 harness fill dispatches
// (~160 us fixed) that kernel_launch cannot remove.
//
// R2: single-variable change vs R1 — REMOVE non-temporal hints (suspected write-path
// regression; the 6.3 TB/s copy ubench and the 6.7 TB/s fills both use plain ops).
// Keep: grid-stride 2048 wg, stride % WVECS == 0 => w/b column invariant per thread,
// loaded once into registers; 4x unrolled independent loads for MLP.

#define IN_FEATURES 4096
#define VEC 4
#define WVECS (IN_FEATURES / VEC)   // 1024 float4-columns, power of 2

#define BLOCK 256
#define GRID 2048                   // 256 CUs x 8; stride = 524288 => stride % 1024 == 0
#define UNROLL 4

typedef float f32x4 __attribute__((ext_vector_type(4)));

__global__ __launch_bounds__(BLOCK) void one_to_one_kernel(
        const f32x4* __restrict__ x,
        const f32x4* __restrict__ w,
        const f32x4* __restrict__ b,
        f32x4* __restrict__ out,
        int nvec) {
    const int tid    = blockIdx.x * BLOCK + (int)threadIdx.x;
    const int stride = GRID * BLOCK;           // 524288 float4s; multiple of WVECS

    // Column invariant across this thread's iterations -> w/b live in registers.
    const int col = tid & (WVECS - 1);
    const f32x4 wv = w[col];
    const f32x4 bv = b[col];

    int i = tid;
    // Main loop: UNROLL independent loads in flight, then UNROLL stores.
    for (; i + (UNROLL - 1) * stride < nvec; i += UNROLL * stride) {
        f32x4 xv[UNROLL];
#pragma unroll
        for (int u = 0; u < UNROLL; ++u)
            xv[u] = x[i + u * stride];
#pragma unroll
        for (int u = 0; u < UNROLL; ++u) {
            f32x4 ov;
            ov.x = fmaf(xv[u].x, wv.x, bv.x);
            ov.y = fmaf(xv[u].y, wv.y, bv.y);
            ov.z = fmaf(xv[u].z, wv.z, bv.z);
            ov.w = fmaf(xv[u].w, wv.w, bv.w);
            out[i + u * stride] = ov;
        }
    }
    // Tail (not taken for 8192x4096: nvec = 16 * stride exactly).
    for (; i < nvec; i += stride) {
        f32x4 xv = x[i];
        f32x4 ov;
        ov.x = fmaf(xv.x, wv.x, bv.x);
        ov.y = fmaf(xv.y, wv.y, bv.y);
        ov.z = fmaf(xv.z, wv.z, bv.z);
        ov.w = fmaf(xv.w, wv.w, bv.w);
        out[i] = ov;
    }
}

extern "C" void kernel_launch(void* const* d_in, const int* in_sizes, int n_in,
                              void* d_out, int out_size, void* d_ws, size_t ws_size,
                              hipStream_t stream) {
    const f32x4* x = (const f32x4*)d_in[0];    // setup_inputs dict order: x, weight, bias
    const f32x4* w = (const f32x4*)d_in[1];
    const f32x4* b = (const f32x4*)d_in[2];
    f32x4* out = (f32x4*)d_out;

    int nvec = out_size / VEC;                 // 33,554,432 / 4 = 8,388,608
    one_to_one_kernel<<<GRID, BLOCK, 0, stream>>>(x, w, b, out, nvec);
}